// Round 10
// baseline (79.608 us; speedup 1.0000x reference)
//
#include <hip/hip_runtime.h>

#define N_NODES 10000
#define FEATS 32
#define HEADS 4
#define SAMPLES 256
#define N_BATCH 2048
#define NGROUP 40                       // ceil(N_NODES / 256)
#define NWORDS (NGROUP * 4)             // 160 u64 words per mask row

typedef float f32x4 __attribute__((ext_vector_type(4)));
typedef unsigned long long u64;

// ws layout (new path):
//   [0)            u64  mask[2048][2][160]   5,242,880 B
//   [5242880)      _Float16 wgt[8192][512]   8,388,608 B   (pair = h*2048+n)
//   [13631488)     float nd[8192][2]            65,536 B   (numA_st, den_st)
#define WS_MASK_BYTES 5242880
#define WS_WGT_OFF    5242880
#define WS_ND_OFF     13631488
#define WS_NEEDED     13697024

// ================= Fused role-split kernel ==================================
// grid 10240: XCD x = bid&7, j = bid>>3 (0..1279 per XCD).
//   j%5==4  -> MASK role (256/XCD, 2048 total): edge n = x*256 + j/5.
//              Build sign bitmasks of edge_mat rows dst (side0, symmetry)
//              and src (side1) with nontemporal streaming loads -> ws_mask.
//   else    -> COMPUTE role (1024/XCD, 8192 total): one (edge, head) pair,
//              h = x&3 (XCD-partitioned: pos[h] = 1.28 MB, L2-resident),
//              n = (x>>2)*1024 + (j/5)*4 + j%5.
//              Wave w handles chunks 2w,2w+1 (side = w>>1). Register-direct
//              4-lane-per-row gathers (R8 batched MLP structure). Computes
//              numA = sum (dot - U)*wgt and den = sum wgt (both 4x-counted),
//              stores per-sample wgt as fp16. NO mask dependency:
//              num_true = numA + 2*U*P with P = sum of wgt where bit=1 (k3).
// Roles interleave in dispatch order (1:4 per XCD) so the mask blocks' HBM
// streaming overlaps the compute blocks' L2/VALU work.
__global__ __launch_bounds__(256) void kbig(
    const int* __restrict__ edge,
    const int* __restrict__ mid0,
    const int* __restrict__ mid1,
    const float* __restrict__ pos,
    const float* __restrict__ field,
    const float* __restrict__ unc,
    const float* __restrict__ edge_mat,
    u64* __restrict__ ws_mask,
    _Float16* __restrict__ ws_wgt,
    float* __restrict__ ws_nd)
{
    const int bid  = blockIdx.x;
    const int x    = bid & 7;     // XCD
    const int j    = bid >> 3;    // position within XCD
    const int tid  = threadIdx.x;
    const int w    = tid >> 6;
    const int lane = tid & 63;

    if (j % 5 == 4) {
        // ---------------- MASK role ----------------
        const int n   = x * 256 + j / 5;
        const int src = edge[2 * n];
        const int dst = edge[2 * n + 1];
        u64* wsn = ws_mask + (size_t)n * 2 * NWORDS;
        #pragma unroll
        for (int r = 0; r < 2; ++r) {
            const float* rp = edge_mat + (size_t)(r ? src : dst) * N_NODES;
            for (int g = w; g < NGROUP; g += 4) {
                int base = g * 256 + lane * 4;
                f32x4 v = {-1.f, -1.f, -1.f, -1.f};
                if (base < N_NODES)
                    v = __builtin_nontemporal_load((const f32x4*)(rp + base));
                u64 b0 = __ballot(v.x > 0.f);
                u64 b1 = __ballot(v.y > 0.f);
                u64 b2 = __ballot(v.z > 0.f);
                u64 b3 = __ballot(v.w > 0.f);
                if (lane < 4) {
                    u64 bb = lane == 0 ? b0 : lane == 1 ? b1
                           : lane == 2 ? b2 : b3;
                    wsn[r * NWORDS + g * 4 + lane] = bb;
                }
            }
        }
        return;
    }

    // ---------------- COMPUTE role ----------------
    __shared__ float s_nd[4][2];

    const int cpos = (j / 5) * 4 + (j % 5);
    const int h    = x & 3;
    const int n    = (x >> 2) * 1024 + cpos;

    const int src = edge[2 * n];
    const int dst = edge[2 * n + 1];
    const float U = unc[0];

    const float* posh   = pos   + (size_t)h * N_NODES * FEATS;
    const float* fieldh = field + (size_t)h * N_NODES * FEATS;

    const int q = lane & 3;    // lane's chunk pair: q and q+4
    const int g = lane >> 2;   // row-group index within 16
    const int side = w >> 1;   // wave-uniform: waves 0,1 -> side0; 2,3 -> side1

    // Anchor/field chunks for this wave's side (4 float4 = 16 VGPRs).
    float4 A0, A1, F0, F1;
    {
        const float4* pa = (const float4*)(posh   + (size_t)(side ? dst : src) * FEATS);
        const float4* pf = (const float4*)(fieldh + (size_t)(side ? src : dst) * FEATS);
        A0 = pa[q]; A1 = pa[q + 4];
        F0 = pf[q]; F1 = pf[q + 4];
    }

    const size_t sb = ((size_t)h * N_BATCH + n) * SAMPLES;
    const int* mids = (w < 2) ? mid0 : mid1;
    int mm0 = mids[sb + (((2 * w)     & 3)) * 64 + lane];
    int mm1 = mids[sb + (((2 * w + 1) & 3)) * 64 + lane];

    const int pair = h * N_BATCH + n;
    _Float16* wgp = ws_wgt + (size_t)pair * 512;

    float num = 0.f, den = 0.f;

    #pragma unroll
    for (int jj = 0; jj < 2; ++jj) {
        const int c   = 2 * w + jj;          // chunk index 0..7
        const int mmc = jj ? mm1 : mm0;

        // Batch phase: all 8 gathers issued before consumption (MLP depth 8).
        int    mArr[4];
        float4 B0[4], B1[4];
        #pragma unroll
        for (int t = 0; t < 4; ++t)
            mArr[t] = __shfl(mmc, t * 16 + g);
        #pragma unroll
        for (int t = 0; t < 4; ++t) {
            const float4* rp = (const float4*)(posh + (size_t)mArr[t] * FEATS);
            B0[t] = rp[q];
            B1[t] = rp[q + 4];
        }

        // Compute phase.
        #pragma unroll
        for (int t = 0; t < 4; ++t) {
            float dh = 0.f, nh = 0.f;
            {
                float dx = A0.x - B0[t].x, dy = A0.y - B0[t].y,
                      dz = A0.z - B0[t].z, dw = A0.w - B0[t].w;
                dh += dx * F0.x + dy * F0.y + dz * F0.z + dw * F0.w;
                nh += dx * dx + dy * dy + dz * dz + dw * dw;
            }
            {
                float dx = A1.x - B1[t].x, dy = A1.y - B1[t].y,
                      dz = A1.z - B1[t].z, dw = A1.w - B1[t].w;
                dh += dx * F1.x + dy * F1.y + dz * F1.z + dw * F1.w;
                nh += dx * dx + dy * dy + dz * dz + dw * dw;
            }
            dh += __shfl_xor(dh, 1); nh += __shfl_xor(nh, 1);
            dh += __shfl_xor(dh, 2); nh += __shfl_xor(nh, 2);

            const float wgt = __expf(1.0f - sqrtf(nh));
            num += (dh - U) * wgt;     // em deferred: num_true = numA + 2U*P
            den += wgt;                // 4x-counted (folded in k3)
            if (q == t)                // 16 lanes store 16 contiguous halfs
                wgp[c * 64 + t * 16 + g] = (_Float16)wgt;
        }
    }

    // Wave-wide butterfly, then block combine (all 4 waves = same pair).
    #pragma unroll
    for (int off = 32; off > 0; off >>= 1) {
        num += __shfl_xor(num, off);
        den += __shfl_xor(den, off);
    }
    if (lane == 0) { s_nd[w][0] = num; s_nd[w][1] = den; }
    __syncthreads();
    if (tid == 0) {
        float na = s_nd[0][0] + s_nd[1][0] + s_nd[2][0] + s_nd[3][0];
        float de = s_nd[0][1] + s_nd[1][1] + s_nd[2][1] + s_nd[3][1];
        ws_nd[pair * 2]     = na;
        ws_nd[pair * 2 + 1] = de;
    }
}

// ================= k3: combine masks + wgt -> out ===========================
// Block n = edge n; wave w = head w. Stage 2.5 KB mask in LDS; per sample,
// P += wgt if bit set. r_h = (numA/4 + 2U*P) / (den/4 + 8); out[n] plain store.
__global__ __launch_bounds__(256) void k3(
    const int* __restrict__ mid0,
    const int* __restrict__ mid1,
    const float* __restrict__ unc,
    const u64* __restrict__ ws_mask,
    const _Float16* __restrict__ ws_wgt,
    const float* __restrict__ ws_nd,
    float* __restrict__ out)
{
    const int n    = blockIdx.x;
    const int tid  = threadIdx.x;
    const int w    = tid >> 6;   // head
    const int lane = tid & 63;

    __shared__ u64 sm[2 * NWORDS];
    __shared__ float sr[HEADS];

    for (int k = tid; k < 2 * NWORDS; k += 256)
        sm[k] = ws_mask[(size_t)n * 2 * NWORDS + k];
    __syncthreads();

    const float U = unc[0];
    const size_t sb = ((size_t)w * N_BATCH + n) * SAMPLES;
    const int pair = w * N_BATCH + n;
    const _Float16* wgp = ws_wgt + (size_t)pair * 512;

    float P = 0.f;
    #pragma unroll
    for (int c = 0; c < 8; ++c) {
        const int m = (c < 4 ? mid0 : mid1)[sb + (c & 3) * 64 + lane];
        const float wv = (float)wgp[c * 64 + lane];
        const int side = c >> 2;
        const u64 wb = sm[side * NWORDS + ((m >> 8) << 2) + (m & 3)];
        if ((wb >> ((m >> 2) & 63)) & 1ull) P += wv;
    }
    #pragma unroll
    for (int off = 32; off > 0; off >>= 1)
        P += __shfl_xor(P, off);

    if (lane == 0) {
        const float numA = ws_nd[pair * 2]     * 0.25f;  // undo 4x counting
        const float W    = ws_nd[pair * 2 + 1] * 0.25f;
        sr[w] = (numA + 2.0f * U * P) / (W + 8.0f);
    }
    __syncthreads();
    if (tid == 0)
        out[n] = 0.25f * (sr[0] + sr[1] + sr[2] + sr[3]);
}

// ================= Fallback path (R8, proven 61.3 us) =======================
__global__ __launch_bounds__(256) void mask_kernel(
    const int* __restrict__ edge,
    const float* __restrict__ edge_mat,
    u64* __restrict__ ws_mask,
    float* __restrict__ out)
{
    const int n    = blockIdx.x;
    const int tid  = threadIdx.x;
    const int wave = tid >> 6;
    const int lane = tid & 63;
    const int src = edge[2 * n];
    const int dst = edge[2 * n + 1];
    if (tid == 0) out[n] = 0.f;
    u64* wsn = ws_mask + (size_t)n * 2 * NWORDS;
    #pragma unroll
    for (int r = 0; r < 2; ++r) {
        const float* rp = edge_mat + (size_t)(r ? src : dst) * N_NODES;
        for (int g = wave; g < NGROUP; g += 4) {
            int base = g * 256 + lane * 4;
            float4 v = make_float4(-1.f, -1.f, -1.f, -1.f);
            if (base < N_NODES) v = *(const float4*)(rp + base);
            u64 b0 = __ballot(v.x > 0.f);
            u64 b1 = __ballot(v.y > 0.f);
            u64 b2 = __ballot(v.z > 0.f);
            u64 b3 = __ballot(v.w > 0.f);
            if (lane < 4) {
                u64 b = lane == 0 ? b0 : lane == 1 ? b1 : lane == 2 ? b2 : b3;
                wsn[r * NWORDS + g * 4 + lane] = b;
            }
        }
    }
}

__global__ __launch_bounds__(256, 4) void madgraph_kernel(
    const int* __restrict__ edge,
    const int* __restrict__ mid0,
    const int* __restrict__ mid1,
    const float* __restrict__ pos,
    const float* __restrict__ field,
    const float* __restrict__ unc,
    const u64* __restrict__ ws_mask,
    float* __restrict__ out)
{
    const int b    = blockIdx.x;
    const int h    = b & 3;
    const int tid  = threadIdx.x;
    const int w    = tid >> 6;
    const int lane = tid & 63;
    const int n    = (b >> 2) + 512 * w;

    __shared__ u64 s_mask[4][2 * NWORDS];

    const int src = edge[2 * n];
    const int dst = edge[2 * n + 1];
    const float U = unc[0];

    const u64* wsn = ws_mask + (size_t)n * 2 * NWORDS;
    #pragma unroll
    for (int k = 0; k < 5; ++k)
        s_mask[w][k * 64 + lane] = wsn[k * 64 + lane];

    const float* posh   = pos   + (size_t)h * N_NODES * FEATS;
    const float* fieldh = field + (size_t)h * N_NODES * FEATS;
    const int q = lane & 3;
    const int g = lane >> 2;

    float4 A[2][2], F[2][2];
    #pragma unroll
    for (int sd = 0; sd < 2; ++sd) {
        const float4* pa = (const float4*)(posh   + (size_t)(sd ? dst : src) * FEATS);
        const float4* pf = (const float4*)(fieldh + (size_t)(sd ? src : dst) * FEATS);
        A[sd][0] = pa[q]; A[sd][1] = pa[q + 4];
        F[sd][0] = pf[q]; F[sd][1] = pf[q + 4];
    }

    const size_t sb = ((size_t)h * N_BATCH + n) * SAMPLES;
    int mm[8];
    #pragma unroll
    for (int c = 0; c < 8; ++c)
        mm[c] = (c < 4 ? mid0 : mid1)[sb + (c & 3) * 64 + lane];

    float num = 0.f, den = 0.f;
    #pragma unroll
    for (int c = 0; c < 8; ++c) {
        const int side = c >> 2;
        int    mArr[4];
        float4 B0[4], B1[4];
        #pragma unroll
        for (int t = 0; t < 4; ++t)
            mArr[t] = __shfl(mm[c], t * 16 + g);
        #pragma unroll
        for (int t = 0; t < 4; ++t) {
            const float4* rp = (const float4*)(posh + (size_t)mArr[t] * FEATS);
            B0[t] = rp[q];
            B1[t] = rp[q + 4];
        }
        #pragma unroll
        for (int t = 0; t < 4; ++t) {
            float dh = 0.f, nh = 0.f;
            {
                float4 a = A[side][0], f = F[side][0];
                float dx = a.x - B0[t].x, dy = a.y - B0[t].y,
                      dz = a.z - B0[t].z, dw = a.w - B0[t].w;
                dh += dx * f.x + dy * f.y + dz * f.z + dw * f.w;
                nh += dx * dx + dy * dy + dz * dz + dw * dw;
            }
            {
                float4 a = A[side][1], f = F[side][1];
                float dx = a.x - B1[t].x, dy = a.y - B1[t].y,
                      dz = a.z - B1[t].z, dw = a.w - B1[t].w;
                dh += dx * f.x + dy * f.y + dz * f.z + dw * f.w;
                nh += dx * dx + dy * dy + dz * dz + dw * dw;
            }
            dh += __shfl_xor(dh, 1); nh += __shfl_xor(nh, 1);
            dh += __shfl_xor(dh, 2); nh += __shfl_xor(nh, 2);
            const u64 wbits =
                s_mask[w][side * NWORDS + ((mArr[t] >> 8) << 2) + (mArr[t] & 3)];
            const float em = ((wbits >> ((mArr[t] >> 2) & 63)) & 1ull) ? U : -U;
            const float wgt = __expf(1.0f - sqrtf(nh));
            num += (dh + em) * wgt;
            den += wgt;
        }
    }
    #pragma unroll
    for (int off = 32; off > 0; off >>= 1) {
        num += __shfl_xor(num, off);
        den += __shfl_xor(den, off);
    }
    if (lane == 0)
        atomicAdd(out + n, 0.25f * (num / (den + 32.0f)));
}

extern "C" void kernel_launch(void* const* d_in, const int* in_sizes, int n_in,
                              void* d_out, int out_size, void* d_ws, size_t ws_size,
                              hipStream_t stream) {
    const int*   edge     = (const int*)  d_in[0];
    const int*   mid0     = (const int*)  d_in[1];
    const int*   mid1     = (const int*)  d_in[2];
    const float* pos      = (const float*)d_in[3];
    const float* field    = (const float*)d_in[4];
    const float* unc      = (const float*)d_in[5];
    const float* edge_mat = (const float*)d_in[6];
    float*       out      = (float*)d_out;

    if (ws_size >= (size_t)WS_NEEDED) {
        u64*      ws_mask = (u64*)d_ws;
        _Float16* ws_wgt  = (_Float16*)((char*)d_ws + WS_WGT_OFF);
        float*    ws_nd   = (float*)((char*)d_ws + WS_ND_OFF);
        kbig<<<10240, 256, 0, stream>>>(edge, mid0, mid1, pos, field, unc,
                                        edge_mat, ws_mask, ws_wgt, ws_nd);
        k3<<<N_BATCH, 256, 0, stream>>>(mid0, mid1, unc, ws_mask, ws_wgt,
                                        ws_nd, out);
    } else {
        u64* ws_mask = (u64*)d_ws;
        mask_kernel<<<N_BATCH, 256, 0, stream>>>(edge, edge_mat, ws_mask, out);
        madgraph_kernel<<<N_BATCH, 256, 0, stream>>>(edge, mid0, mid1, pos,
                                                     field, unc, ws_mask, out);
    }
}